// Round 1
// 1439.243 us; speedup vs baseline: 1.0146x; 1.0146x over previous
//
#include <hip/hip_runtime.h>
#include <math.h>

// Problem constants (from reference): D=256, E=1024, F=1024, N=4096.
// out[n,f] = sum_d x[n,d] * W_eff[d,f] + b_eff[f]
//   W_eff[d,f] = sum_e w[e,f] * expert_W[e,d,f]   (w = softmax(x[:1024] @ gate_W + gate_b))
//   b_eff[f]   = sum_e w[e,f] * expert_b[e,f]
//
// ws layout (floats):
//   [0, 1048576)            : w      (1024 x 1024)
//   [1048576, 1048576+257K) : weff   (257 x 1024); rows 0..255 = W_eff, row 256 = b_eff
// total ~5.03 MB of d_ws used.

#define DD 256
#define EE 1024
#define FF 1024
#define NN 4096

typedef float f32x4 __attribute__((ext_vector_type(4)));

// ---------------- Kernel A: gate GEMM + row softmax (rows 0..1023 only) ----------------
// grid 256 blocks x 256 threads; each block does 4 rows x 1024 cols.
__global__ __launch_bounds__(256) void gate_kernel(const float* __restrict__ x,
                                                   const float* __restrict__ gW,
                                                   const float* __restrict__ gb,
                                                   float* __restrict__ w_out) {
    __shared__ float xs[4 * DD];       // 4 KB
    __shared__ float ls[4 * EE];       // 16 KB logits
    const int tid = threadIdx.x;
    const int r0 = blockIdx.x * 4;

    // load 4 rows of x (1024 floats) -> one float4 per thread
    ((float4*)xs)[tid] = ((const float4*)(x + (size_t)r0 * DD))[tid];
    __syncthreads();

    float4 a0 = {0,0,0,0}, a1 = {0,0,0,0}, a2 = {0,0,0,0}, a3 = {0,0,0,0};
    const float4* gw4 = (const float4*)gW;   // row d: d*256 float4s; this thread's cols = float4 #tid
    #pragma unroll 4
    for (int d = 0; d < DD; ++d) {
        float4 g = gw4[d * 256 + tid];
        float x0 = xs[0*DD + d], x1 = xs[1*DD + d], x2 = xs[2*DD + d], x3 = xs[3*DD + d];
        a0.x += x0*g.x; a0.y += x0*g.y; a0.z += x0*g.z; a0.w += x0*g.w;
        a1.x += x1*g.x; a1.y += x1*g.y; a1.z += x1*g.z; a1.w += x1*g.w;
        a2.x += x2*g.x; a2.y += x2*g.y; a2.z += x2*g.z; a2.w += x2*g.w;
        a3.x += x3*g.x; a3.y += x3*g.y; a3.z += x3*g.z; a3.w += x3*g.w;
    }
    float4 b = ((const float4*)gb)[tid];
    a0.x += b.x; a0.y += b.y; a0.z += b.z; a0.w += b.w;
    a1.x += b.x; a1.y += b.y; a1.z += b.z; a1.w += b.w;
    a2.x += b.x; a2.y += b.y; a2.z += b.z; a2.w += b.w;
    a3.x += b.x; a3.y += b.y; a3.z += b.z; a3.w += b.w;
    ((float4*)&ls[0*EE])[tid] = a0;
    ((float4*)&ls[1*EE])[tid] = a1;
    ((float4*)&ls[2*EE])[tid] = a2;
    ((float4*)&ls[3*EE])[tid] = a3;
    __syncthreads();

    // softmax: one wave (64 lanes) per row; 16 values per lane, stride 64
    const int lane = tid & 63;
    const int row = tid >> 6;    // 0..3
    float vals[16];
    float m = -3.0e38f;
    #pragma unroll
    for (int i = 0; i < 16; ++i) {
        vals[i] = ls[row * EE + i * 64 + lane];
        m = fmaxf(m, vals[i]);
    }
    #pragma unroll
    for (int off = 1; off < 64; off <<= 1) m = fmaxf(m, __shfl_xor(m, off));
    float s = 0.0f;
    #pragma unroll
    for (int i = 0; i < 16; ++i) {
        vals[i] = __expf(vals[i] - m);
        s += vals[i];
    }
    #pragma unroll
    for (int off = 1; off < 64; off <<= 1) s += __shfl_xor(s, off);
    const float inv = 1.0f / s;
    float* wrow = w_out + (size_t)(r0 + row) * EE;
    #pragma unroll
    for (int i = 0; i < 16; ++i) wrow[i * 64 + lane] = vals[i] * inv;
}

// ---------------- Kernel B: W_eff / b_eff reduction (HBM-bound streaming) ----------------
// New structure: amortize w reads 8x and read expert_W in 32 KB contiguous bursts.
//   blocks 0..15    : b_eff, e-chunk of 64 (e0 = b*64)
//   blocks 16..527  : main; m = b-16; dgroup = m>>4 (8 d-slices), echunk = m&15 (64 e's)
// Per main block per e-iteration: 1 float4 of w (L2-resident, reused 8x) +
// 8 consecutive 4 KB rows of expert_W (nontemporal: streamed once, don't evict w from L2).
// HBM traffic: 512 blocks x 2 MB = 1.07 GB expert_W (irreducible) + 134 MB w (cache-side).
__global__ __launch_bounds__(256) void weff_kernel(const float* __restrict__ eW,
                                                   const float* __restrict__ eb,
                                                   const float* __restrict__ w,
                                                   float* __restrict__ weff) {
    const int tid = threadIdx.x;
    const int f = tid * 4;
    const int b = blockIdx.x;

    if (b < 16) {
        // ---- b_eff partial: e in [b*64, b*64+64) ----
        const int e0 = b * 64;
        const float* pw = w  + (size_t)e0 * EE + f;
        const float* pb = eb + (size_t)e0 * FF + f;
        f32x4 acc = {0.f, 0.f, 0.f, 0.f};
        #pragma unroll 4
        for (int i = 0; i < 64; ++i) {
            f32x4 wv = *(const f32x4*)pw;
            f32x4 a  = __builtin_nontemporal_load((const f32x4*)pb);
            acc += wv * a;
            pw += EE;
            pb += FF;
        }
        float* dst = weff + (size_t)DD * FF + f;
        atomicAdd(dst + 0, acc.x);
        atomicAdd(dst + 1, acc.y);
        atomicAdd(dst + 2, acc.z);
        atomicAdd(dst + 3, acc.w);
        return;
    }

    const int m = b - 16;
    const int dgroup = m >> 4;      // 0..31 -> d0 = dgroup*8
    const int echunk = m & 15;      // 0..15 -> e0 = echunk*64
    const int e0 = echunk * 64;
    const int d0 = dgroup * 8;

    const float* pw = w  + (size_t)e0 * EE + f;
    const float* pe = eW + (size_t)e0 * DD * FF + (size_t)d0 * FF + f;

    f32x4 acc[8];
    #pragma unroll
    for (int k = 0; k < 8; ++k) acc[k] = (f32x4){0.f, 0.f, 0.f, 0.f};

    #pragma unroll 2
    for (int i = 0; i < 64; ++i) {
        f32x4 wv = *(const f32x4*)pw;
        f32x4 a[8];
        #pragma unroll
        for (int k = 0; k < 8; ++k)
            a[k] = __builtin_nontemporal_load((const f32x4*)(pe + (size_t)k * FF));
        #pragma unroll
        for (int k = 0; k < 8; ++k)
            acc[k] += wv * a[k];
        pw += EE;
        pe += (size_t)DD * FF;
    }

    #pragma unroll
    for (int k = 0; k < 8; ++k) {
        float* dst = weff + (size_t)(d0 + k) * FF + f;
        atomicAdd(dst + 0, acc[k].x);
        atomicAdd(dst + 1, acc[k].y);
        atomicAdd(dst + 2, acc[k].z);
        atomicAdd(dst + 3, acc[k].w);
    }
}

// ---------------- Kernel C: out = x @ W_eff + b_eff ----------------
// grid 512 blocks x 256 threads; block = 8 rows x 1024 cols (2 blocks/CU for latency hiding).
__global__ __launch_bounds__(256) void out_kernel(const float* __restrict__ x,
                                                  const float* __restrict__ weff,
                                                  float* __restrict__ out) {
    __shared__ float xs[8 * DD];   // 8 KB
    const int tid = threadIdx.x;
    const int n0 = blockIdx.x * 8;

    // load 8x256 x-tile = 512 float4, 2 per thread
    {
        const f32x4* xsrc = (const f32x4*)(x + (size_t)n0 * DD);
        f32x4* xd = (f32x4*)xs;
        #pragma unroll
        for (int k = 0; k < 2; ++k) xd[tid + k * 256] = xsrc[tid + k * 256];
    }
    __syncthreads();

    f32x4 acc[8];
    #pragma unroll
    for (int r = 0; r < 8; ++r) acc[r] = (f32x4){0.f, 0.f, 0.f, 0.f};

    const f32x4* wp = (const f32x4*)weff + tid;   // row d at d*256 float4s
    #pragma unroll 4
    for (int d = 0; d < DD; ++d) {
        f32x4 g = wp[(size_t)d * 256];
        #pragma unroll
        for (int r = 0; r < 8; ++r) {
            float xv = xs[r * DD + d];   // LDS broadcast (same addr across lanes)
            acc[r] += g * xv;
        }
    }

    f32x4 bv = ((const f32x4*)(weff + (size_t)DD * FF))[tid];   // b_eff row
    #pragma unroll
    for (int r = 0; r < 8; ++r) {
        f32x4 o = acc[r] + bv;
        __builtin_nontemporal_store(o, (f32x4*)(out + (size_t)(n0 + r) * FF) + tid);
    }
}

extern "C" void kernel_launch(void* const* d_in, const int* in_sizes, int n_in,
                              void* d_out, int out_size, void* d_ws, size_t ws_size,
                              hipStream_t stream) {
    const float* x  = (const float*)d_in[0];
    const float* gW = (const float*)d_in[1];
    const float* gb = (const float*)d_in[2];
    const float* eW = (const float*)d_in[3];
    const float* eb = (const float*)d_in[4];
    float* out = (float*)d_out;

    float* ws   = (float*)d_ws;
    float* w    = ws;                       // 1024*1024 floats
    float* weff = ws + (size_t)EE * EE;     // 257*1024 floats

    // weff is accumulated with atomics -> must be zeroed every call (ws is re-poisoned)
    hipMemsetAsync(weff, 0, (size_t)(DD + 1) * FF * sizeof(float), stream);

    gate_kernel<<<dim3(256), dim3(256), 0, stream>>>(x, gW, gb, w);
    weff_kernel<<<dim3(528), dim3(256), 0, stream>>>(eW, eb, w, weff);
    out_kernel<<<dim3(512), dim3(256), 0, stream>>>(x, weff, out);
}

// Round 2
// 1394.411 us; speedup vs baseline: 1.0472x; 1.0322x over previous
//
#include <hip/hip_runtime.h>
#include <math.h>

// Problem constants (from reference): D=256, E=1024, F=1024, N=4096.
// out[n,f] = sum_d x[n,d] * W_eff[d,f] + b_eff[f]
//   W_eff[d,f] = sum_e w[e,f] * expert_W[e,d,f]   (w = softmax(x[:1024] @ gate_W + gate_b))
//   b_eff[f]   = sum_e w[e,f] * expert_b[e,f]
//
// ws layout (floats):
//   [0, 1048576)               : w      (1024 x 1024)
//   [1048576, 1311744)         : weff   (257 x 1024); rows 0..255 = W_eff, row 256 = b_eff
//   [1311744, 1311744+8421376) : part   (32 x 257 x 1024) race-free partials, no atomics
// total ~39 MB of d_ws used. No memset needed: every partial slot written exactly once.

#define DD 256
#define EE 1024
#define FF 1024
#define NN 4096

typedef float f32x4 __attribute__((ext_vector_type(4)));

// ---------------- Kernel A: gate GEMM + row softmax (rows 0..1023 only) ----------------
// grid 256 blocks x 256 threads; each block does 4 rows x 1024 cols.
__global__ __launch_bounds__(256) void gate_kernel(const float* __restrict__ x,
                                                   const float* __restrict__ gW,
                                                   const float* __restrict__ gb,
                                                   float* __restrict__ w_out) {
    __shared__ float xs[4 * DD];       // 4 KB
    __shared__ float ls[4 * EE];       // 16 KB logits
    const int tid = threadIdx.x;
    const int r0 = blockIdx.x * 4;

    // load 4 rows of x (1024 floats) -> one float4 per thread
    ((float4*)xs)[tid] = ((const float4*)(x + (size_t)r0 * DD))[tid];
    __syncthreads();

    float4 a0 = {0,0,0,0}, a1 = {0,0,0,0}, a2 = {0,0,0,0}, a3 = {0,0,0,0};
    const float4* gw4 = (const float4*)gW;   // row d: d*256 float4s; this thread's cols = float4 #tid
    #pragma unroll 4
    for (int d = 0; d < DD; ++d) {
        float4 g = gw4[d * 256 + tid];
        float x0 = xs[0*DD + d], x1 = xs[1*DD + d], x2 = xs[2*DD + d], x3 = xs[3*DD + d];
        a0.x += x0*g.x; a0.y += x0*g.y; a0.z += x0*g.z; a0.w += x0*g.w;
        a1.x += x1*g.x; a1.y += x1*g.y; a1.z += x1*g.z; a1.w += x1*g.w;
        a2.x += x2*g.x; a2.y += x2*g.y; a2.z += x2*g.z; a2.w += x2*g.w;
        a3.x += x3*g.x; a3.y += x3*g.y; a3.z += x3*g.z; a3.w += x3*g.w;
    }
    float4 b = ((const float4*)gb)[tid];
    a0.x += b.x; a0.y += b.y; a0.z += b.z; a0.w += b.w;
    a1.x += b.x; a1.y += b.y; a1.z += b.z; a1.w += b.w;
    a2.x += b.x; a2.y += b.y; a2.z += b.z; a2.w += b.w;
    a3.x += b.x; a3.y += b.y; a3.z += b.z; a3.w += b.w;
    ((float4*)&ls[0*EE])[tid] = a0;
    ((float4*)&ls[1*EE])[tid] = a1;
    ((float4*)&ls[2*EE])[tid] = a2;
    ((float4*)&ls[3*EE])[tid] = a3;
    __syncthreads();

    // softmax: one wave (64 lanes) per row; 16 values per lane, stride 64
    const int lane = tid & 63;
    const int row = tid >> 6;    // 0..3
    float vals[16];
    float m = -3.0e38f;
    #pragma unroll
    for (int i = 0; i < 16; ++i) {
        vals[i] = ls[row * EE + i * 64 + lane];
        m = fmaxf(m, vals[i]);
    }
    #pragma unroll
    for (int off = 1; off < 64; off <<= 1) m = fmaxf(m, __shfl_xor(m, off));
    float s = 0.0f;
    #pragma unroll
    for (int i = 0; i < 16; ++i) {
        vals[i] = __expf(vals[i] - m);
        s += vals[i];
    }
    #pragma unroll
    for (int off = 1; off < 64; off <<= 1) s += __shfl_xor(s, off);
    const float inv = 1.0f / s;
    float* wrow = w_out + (size_t)(r0 + row) * EE;
    #pragma unroll
    for (int i = 0; i < 16; ++i) wrow[i * 64 + lane] = vals[i] * inv;
}

// ---------------- Kernel B1: W_eff / b_eff partials (HBM-bound streaming, NO atomics) ----
//   blocks 0..31     : b_eff partial, ec = b, e in [ec*32, ec*32+32)
//   blocks 32..1055  : main; m = b-32; dg = m>>5 (8 d-slices), ec = m&31 (32 e's)
// 1024 main blocks = 4 blocks/CU = 16 waves/CU (2x round-1 MLP).
// Per main block: 32 iters x {1 float4 of w (L2-resident, reused 8x) +
// 8 consecutive 4 KB rows of eW NT (32 KB contiguous burst)}.
// Each partial slot part[ec][slice][f] is written by exactly one block -> race-free.
__global__ __launch_bounds__(256) void weff_partial_kernel(const float* __restrict__ eW,
                                                           const float* __restrict__ eb,
                                                           const float* __restrict__ w,
                                                           float* __restrict__ part) {
    const int tid = threadIdx.x;
    const int f = tid * 4;
    const int b = blockIdx.x;

    if (b < 32) {
        // ---- b_eff partial: e in [b*32, b*32+32) ----
        const int ec = b;
        const int e0 = ec * 32;
        const float* pw = w  + (size_t)e0 * EE + f;
        const float* pb = eb + (size_t)e0 * FF + f;
        f32x4 acc = {0.f, 0.f, 0.f, 0.f};
        #pragma unroll 4
        for (int i = 0; i < 32; ++i) {
            f32x4 wv = *(const f32x4*)pw;
            f32x4 a  = __builtin_nontemporal_load((const f32x4*)pb);
            acc += wv * a;
            pw += EE;
            pb += FF;
        }
        *(f32x4*)(part + (size_t)ec * (257 * FF) + (size_t)256 * FF + f) = acc;
        return;
    }

    const int m = b - 32;
    const int dg = m >> 5;          // 0..31 -> d0 = dg*8
    const int ec = m & 31;          // 0..31 -> e0 = ec*32
    const int e0 = ec * 32;
    const int d0 = dg * 8;

    const float* pw = w  + (size_t)e0 * EE + f;
    const float* pe = eW + (size_t)e0 * DD * FF + (size_t)d0 * FF + f;

    f32x4 acc[8];
    #pragma unroll
    for (int k = 0; k < 8; ++k) acc[k] = (f32x4){0.f, 0.f, 0.f, 0.f};

    #pragma unroll 2
    for (int i = 0; i < 32; ++i) {
        f32x4 wv = *(const f32x4*)pw;
        f32x4 a[8];
        #pragma unroll
        for (int k = 0; k < 8; ++k)
            a[k] = __builtin_nontemporal_load((const f32x4*)(pe + (size_t)k * FF));
        #pragma unroll
        for (int k = 0; k < 8; ++k)
            acc[k] += wv * a[k];
        pw += EE;
        pe += (size_t)DD * FF;
    }

    float* dst = part + (size_t)ec * (257 * FF) + (size_t)d0 * FF + f;
    #pragma unroll
    for (int k = 0; k < 8; ++k)
        *(f32x4*)(dst + (size_t)k * FF) = acc[k];
}

// ---------------- Kernel B2: reduce partials -> weff ----------------
// grid 257 blocks x 256 threads; weff[slice][f] = sum_ec part[ec][slice][f].
// 33.6 MB read (L2/LLC-resident, just written), 1 MB written. ~10 us.
__global__ __launch_bounds__(256) void weff_reduce_kernel(const float* __restrict__ part,
                                                          float* __restrict__ weff) {
    const int tid = threadIdx.x;
    const int slice = blockIdx.x;   // 0..256
    const float* p = part + (size_t)slice * FF + (size_t)tid * 4;
    f32x4 acc = {0.f, 0.f, 0.f, 0.f};
    #pragma unroll 8
    for (int ec = 0; ec < 32; ++ec) {
        acc += __builtin_nontemporal_load((const f32x4*)p);
        p += (size_t)257 * FF;
    }
    *(f32x4*)(weff + (size_t)slice * FF + (size_t)tid * 4) = acc;
}

// ---------------- Kernel C: out = x @ W_eff + b_eff ----------------
// grid 512 blocks x 256 threads; block = 8 rows x 1024 cols (2 blocks/CU for latency hiding).
__global__ __launch_bounds__(256) void out_kernel(const float* __restrict__ x,
                                                  const float* __restrict__ weff,
                                                  float* __restrict__ out) {
    __shared__ float xs[8 * DD];   // 8 KB
    const int tid = threadIdx.x;
    const int n0 = blockIdx.x * 8;

    // load 8x256 x-tile = 512 float4, 2 per thread
    {
        const f32x4* xsrc = (const f32x4*)(x + (size_t)n0 * DD);
        f32x4* xd = (f32x4*)xs;
        #pragma unroll
        for (int k = 0; k < 2; ++k) xd[tid + k * 256] = xsrc[tid + k * 256];
    }
    __syncthreads();

    f32x4 acc[8];
    #pragma unroll
    for (int r = 0; r < 8; ++r) acc[r] = (f32x4){0.f, 0.f, 0.f, 0.f};

    const f32x4* wp = (const f32x4*)weff + tid;   // row d at d*256 float4s
    #pragma unroll 4
    for (int d = 0; d < DD; ++d) {
        f32x4 g = wp[(size_t)d * 256];
        #pragma unroll
        for (int r = 0; r < 8; ++r) {
            float xv = xs[r * DD + d];   // LDS broadcast (same addr across lanes)
            acc[r] += g * xv;
        }
    }

    f32x4 bv = ((const f32x4*)(weff + (size_t)DD * FF))[tid];   // b_eff row
    #pragma unroll
    for (int r = 0; r < 8; ++r) {
        f32x4 o = acc[r] + bv;
        __builtin_nontemporal_store(o, (f32x4*)(out + (size_t)(n0 + r) * FF) + tid);
    }
}

extern "C" void kernel_launch(void* const* d_in, const int* in_sizes, int n_in,
                              void* d_out, int out_size, void* d_ws, size_t ws_size,
                              hipStream_t stream) {
    const float* x  = (const float*)d_in[0];
    const float* gW = (const float*)d_in[1];
    const float* gb = (const float*)d_in[2];
    const float* eW = (const float*)d_in[3];
    const float* eb = (const float*)d_in[4];
    float* out = (float*)d_out;

    float* ws   = (float*)d_ws;
    float* w    = ws;                                   // 1024*1024 floats
    float* weff = ws + (size_t)EE * EE;                 // 257*1024 floats
    float* part = weff + (size_t)(DD + 1) * FF;         // 32*257*1024 floats

    // No memset: partials are write-once, reduce overwrites weff fully.
    gate_kernel<<<dim3(256), dim3(256), 0, stream>>>(x, gW, gb, w);
    weff_partial_kernel<<<dim3(1056), dim3(256), 0, stream>>>(eW, eb, w, part);
    weff_reduce_kernel<<<dim3(257), dim3(256), 0, stream>>>(part, weff);
    out_kernel<<<dim3(512), dim3(256), 0, stream>>>(x, weff, out);
}